// Round 1
// baseline (220.608 us; speedup 1.0000x reference)
//
#include <hip/hip_runtime.h>
#include <stdint.h>

#define N_NODES 100000
#define D_FEAT  128
#define N_EDGES 500000
#define HIDDEN  256
#define EPT     64                                   // edges per super-tile
#define NTILES  ((N_EDGES + EPT - 1) / EPT)          // 7813 (last tile has 32)
#define GRID_MAIN 256

typedef __bf16 bf16x8 __attribute__((ext_vector_type(8)));
typedef float  f32x4  __attribute__((ext_vector_type(4)));

__device__ __forceinline__ unsigned short f2bf(float f) {
  unsigned u = __builtin_bit_cast(unsigned, f);
  u += 0x7FFFu + ((u >> 16) & 1u);                   // round-nearest-even
  return (unsigned short)(u >> 16);
}

// convert 4*n4 floats -> bf16
__global__ void cvt_bf16(const float* __restrict__ src,
                         unsigned short* __restrict__ dst, int n4) {
  int i = blockIdx.x * blockDim.x + threadIdx.x;
  const int stride = gridDim.x * blockDim.x;
  for (; i < n4; i += stride) {
    const float4 v = ((const float4*)src)[i];
    union { unsigned short s[4]; uint2 u; } o;
    o.s[0] = f2bf(v.x); o.s[1] = f2bf(v.y);
    o.s[2] = f2bf(v.z); o.s[3] = f2bf(v.w);
    ((uint2*)dst)[i] = o.u;
  }
}

// int64-vs-int32 edge_index probe: int64 (values < 2^31) has zero high words.
__global__ void detect_idx(const int* __restrict__ e, int* __restrict__ flag) {
  if (blockIdx.x == 0 && threadIdx.x == 0)
    *flag = (e[1] == 0 && e[3] == 0 && e[5] == 0) ? 1 : 0;
}

// xT = relu(W1 * concatT + b1); out = sigmoid(w2 . x + b2)
// 8 waves; wave w owns hidden rows [32w, 32w+32) with W1 frags in registers.
__global__ __launch_bounds__(512, 2)
void mlp_edges(const int* __restrict__ eidx,
               const unsigned short* __restrict__ z16,    // [N_NODES][128] bf16
               const unsigned short* __restrict__ w116,   // [256][256] bf16 row-major [n][k]
               const float* __restrict__ b1,
               const float* __restrict__ w2g,
               const float* __restrict__ b2,
               const int* __restrict__ flagp,
               float* __restrict__ out) {
  __shared__ unsigned char sbuf[2][EPT * 512];   // 2 x 32 KiB feature tiles (XOR-swizzled)
  __shared__ float b1f[HIDDEN];
  __shared__ float w2f[HIDDEN];
  __shared__ float red[8][EPT];

  const int tid = threadIdx.x;
  const int w   = tid >> 6;        // wave 0..7
  const int l   = tid & 63;
  const int l15 = l & 15;
  const int l31 = l & 31;

  if (tid < HIDDEN) { b1f[tid] = b1[tid]; w2f[tid] = w2g[tid]; }
  const int   is64 = *flagp;
  const float b2v  = b2[0];

  // Permanent A fragments (W1): A[n][k], lane: n = base + (l&15), k = ks*32 + (l>>4)*8 .. +7
  bf16x8 a[2][8];
  #pragma unroll
  for (int rt = 0; rt < 2; ++rt) {
    const int n = w * 32 + rt * 16 + l15;
    #pragma unroll
    for (int ks = 0; ks < 8; ++ks) {
      const int k = ks * 32 + (l >> 4) * 8;
      a[rt][ks] = *(const bf16x8*)(w116 + n * 256 + k);
    }
  }

  const int t0 = blockIdx.x;
  // prologue: stage tile t0 into sbuf[0]
  {
    #pragma unroll
    for (int ii = 0; ii < 4; ++ii) {
      const int i = w * 4 + ii;                 // staging instr 0..31
      const int m = 2 * i + (l >> 5);           // edge slot 0..63
      int e = t0 * EPT + m;
      if (e >= N_EDGES) e = N_EDGES - 1;
      const int half = (l31 >> 4);              // 0: z[row] (k<128), 1: z[col]
      const int iv = is64 ? eidx[6 * e + 2 + 2 * half]
                          : eidx[3 * e + 1 + half];
      const int off = ((l31 * 16) ^ ((m & 7) << 4)) & 255;  // pre-swizzled source
      const uint4 v = *(const uint4*)((const char*)(z16 + iv * D_FEAT) + off);
      *(uint4*)&sbuf[0][i * 1024 + l * 16] = v;  // linear dest
    }
  }
  __syncthreads();

  int cur = 0;
  for (int t = t0; t < NTILES; t += GRID_MAIN) {
    const int tn = t + GRID_MAIN;
    const bool hasNext = (tn < NTILES);

    // T14 split: issue next-tile gathers now, ds_write after the barrier
    uint4 stg[4];
    if (hasNext) {
      #pragma unroll
      for (int ii = 0; ii < 4; ++ii) {
        const int i = w * 4 + ii;
        const int m = 2 * i + (l >> 5);
        int e = tn * EPT + m;
        if (e >= N_EDGES) e = N_EDGES - 1;
        const int half = (l31 >> 4);
        const int iv = is64 ? eidx[6 * e + 2 + 2 * half]
                            : eidx[3 * e + 1 + half];
        const int off = ((l31 * 16) ^ ((m & 7) << 4)) & 255;
        stg[ii] = *(const uint4*)((const char*)(z16 + iv * D_FEAT) + off);
      }
    }

    // ---- MFMA phase: D[n][m] += sum_k W1[n][k] * feat[m][k] ----
    f32x4 acc[2][4];
    #pragma unroll
    for (int rt = 0; rt < 2; ++rt)
      #pragma unroll
      for (int ct = 0; ct < 4; ++ct)
        acc[rt][ct] = (f32x4){0.f, 0.f, 0.f, 0.f};

    const unsigned char* sb = &sbuf[cur][0];
    #pragma unroll
    for (int ks = 0; ks < 8; ++ks) {
      bf16x8 bf[4];
      #pragma unroll
      for (int ct = 0; ct < 4; ++ct) {
        const int m     = ct * 16 + l15;
        const int inrow = ks * 64 + (l >> 4) * 16;
        const int phys  = m * 512 + (inrow ^ ((m & 7) << 4));
        bf[ct] = *(const bf16x8*)(sb + phys);    // ds_read_b128, conflict-free
      }
      #pragma unroll
      for (int rt = 0; rt < 2; ++rt)
        #pragma unroll
        for (int ct = 0; ct < 4; ++ct)
          acc[rt][ct] = __builtin_amdgcn_mfma_f32_16x16x32_bf16(
              a[rt][ks], bf[ct], acc[rt][ct], 0, 0, 0);
    }

    // ---- epilogue: bias + relu + fc2 partial dot ----
    float p[4] = {0.f, 0.f, 0.f, 0.f};
    #pragma unroll
    for (int rt = 0; rt < 2; ++rt) {
      const int nb = w * 32 + rt * 16 + (l >> 4) * 4;
      const f32x4 b1v = *(const f32x4*)&b1f[nb];
      const f32x4 w2v = *(const f32x4*)&w2f[nb];
      #pragma unroll
      for (int r = 0; r < 4; ++r) {
        #pragma unroll
        for (int ct = 0; ct < 4; ++ct) {
          float x = acc[rt][ct][r] + b1v[r];     // n = nb + r
          x = fmaxf(x, 0.f);
          p[ct] = fmaf(x, w2v[r], p[ct]);
        }
      }
    }
    #pragma unroll
    for (int ct = 0; ct < 4; ++ct) {             // sum over the 4 (l>>4) groups
      p[ct] += __shfl_xor(p[ct], 16);
      p[ct] += __shfl_xor(p[ct], 32);
    }
    if (l < 16) {
      #pragma unroll
      for (int ct = 0; ct < 4; ++ct) red[w][ct * 16 + l] = p[ct];
    }
    __syncthreads();

    if (hasNext) {                               // late LDS write of next tile
      #pragma unroll
      for (int ii = 0; ii < 4; ++ii) {
        const int i = w * 4 + ii;
        *(uint4*)&sbuf[cur ^ 1][i * 1024 + l * 16] = stg[ii];
      }
    }
    if (tid < EPT) {                             // cross-wave sum + sigmoid
      const int e = t * EPT + tid;
      if (e < N_EDGES) {
        float s = b2v;
        #pragma unroll
        for (int ww = 0; ww < 8; ++ww) s += red[ww][tid];
        out[e] = 1.f / (1.f + expf(-s));
      }
    }
    __syncthreads();
    cur ^= 1;
  }
}

extern "C" void kernel_launch(void* const* d_in, const int* in_sizes, int n_in,
                              void* d_out, int out_size, void* d_ws, size_t ws_size,
                              hipStream_t stream) {
  const float* z    = (const float*)d_in[0];
  const int*   eidx = (const int*)d_in[1];
  const float* fc1w = (const float*)d_in[2];
  const float* fc1b = (const float*)d_in[3];
  const float* fc2w = (const float*)d_in[4];
  const float* fc2b = (const float*)d_in[5];
  float* out = (float*)d_out;

  unsigned char* ws = (unsigned char*)d_ws;
  unsigned short* z16  = (unsigned short*)ws;                     // 25,600,000 B
  unsigned short* w116 = (unsigned short*)(ws + 25600000);        // 131,072 B
  int*            flag = (int*)(ws + 25600000 + 131072);          // 4 B

  cvt_bf16<<<2048, 256, 0, stream>>>(z, z16, N_NODES * D_FEAT / 4);
  cvt_bf16<<<64, 256, 0, stream>>>(fc1w, w116, HIDDEN * 256 / 4);
  detect_idx<<<1, 64, 0, stream>>>(eidx, flag);
  mlp_edges<<<GRID_MAIN, 512, 0, stream>>>(eidx, z16, w116, fc1b, fc2w, fc2b,
                                           flag, out);
}

// Round 2
// 176.217 us; speedup vs baseline: 1.2519x; 1.2519x over previous
//
#include <hip/hip_runtime.h>
#include <stdint.h>

#define N_NODES 100000
#define D_FEAT  128
#define N_EDGES 500000
#define HIDDEN  256
#define EPT     64                                   // edges per tile
#define NTILES  ((N_EDGES + EPT - 1) / EPT)          // 7813
#define GRID_MAIN 256

typedef __bf16 bf16x8 __attribute__((ext_vector_type(8)));
typedef float  f32x4  __attribute__((ext_vector_type(4)));

__device__ __forceinline__ unsigned short f2bf(float f) {
  unsigned u = __builtin_bit_cast(unsigned, f);
  u += 0x7FFFu + ((u >> 16) & 1u);                   // round-nearest-even
  return (unsigned short)(u >> 16);
}

__device__ __forceinline__ uint4 pack8(float4 a, float4 b) {
  union { unsigned short s[8]; uint4 u; } o;
  o.s[0] = f2bf(a.x); o.s[1] = f2bf(a.y); o.s[2] = f2bf(a.z); o.s[3] = f2bf(a.w);
  o.s[4] = f2bf(b.x); o.s[5] = f2bf(b.y); o.s[6] = f2bf(b.z); o.s[7] = f2bf(b.w);
  return o.u;
}

// xT = relu(W1 * concatT + b1); out = sigmoid(w2 . x + b2)
// 8 waves; wave w owns hidden rows [32w,32w+32), W1 frags register-resident.
// Triple-buffered feature LDS, ONE barrier per tile, depth-2 gather prefetch.
__global__ __launch_bounds__(512, 2)
void mlp_fused(const int* __restrict__ eidx,
               const float* __restrict__ zf,      // [N_NODES][128] f32
               const float* __restrict__ w1f,     // [256][256] f32
               const float* __restrict__ b1,
               const float* __restrict__ w2g,
               const float* __restrict__ b2,
               float* __restrict__ out) {
  __shared__ unsigned char sbuf[3][EPT * 512];     // 3 x 32 KiB (XOR-swizzled)
  __shared__ float red[2][8][72];                  // parity-buffered partials

  const int tid = threadIdx.x;
  const int w   = tid >> 6;        // wave 0..7
  const int l   = tid & 63;
  const int l15 = l & 15;
  const int g   = l >> 4;          // k-slice group 0..3
  const int si  = w * 4;           // first staging slot of this wave
  const int half = (l & 31) >> 4;  // 0: z[row], 1: z[col]

  // int64-vs-int32 probe (uniform): int64 indices have zero high words.
  const int is64 = (eidx[1] == 0 && eidx[3] == 0 && eidx[5] == 0);
  const float b2v = b2[0];

  // ---- W1 fragments (f32 -> bf16 RNE), register-resident ----
  // A[n][k]: n = w*32 + rt*16 + (l&15), k = ks*32 + g*8 .. +7
  bf16x8 a[2][8];
  #pragma unroll
  for (int rt = 0; rt < 2; ++rt) {
    const int n = w * 32 + rt * 16 + l15;
    #pragma unroll
    for (int ks = 0; ks < 8; ++ks) {
      const int k = ks * 32 + g * 8;
      const float4 lo = *(const float4*)(w1f + n * 256 + k);
      const float4 hi = *(const float4*)(w1f + n * 256 + k + 4);
      a[rt][ks] = __builtin_bit_cast(bf16x8, pack8(lo, hi));
    }
  }
  // bias / fc2 weights for this lane's accumulator rows
  f32x4 b1v[2], w2v[2];
  #pragma unroll
  for (int rt = 0; rt < 2; ++rt) {
    const int nb = w * 32 + rt * 16 + g * 4;
    b1v[rt] = *(const f32x4*)(b1 + nb);
    w2v[rt] = *(const f32x4*)(w2g + nb);
  }

  // gather one tile's features (f32) into regs; lane covers 32B of a node row
  auto gather = [&](int tt, float4* ga, float4* gb) {
    #pragma unroll
    for (int ii = 0; ii < 4; ++ii) {
      const int i = si + ii;
      const int m = 2 * i + (l >> 5);              // edge slot 0..63
      int e = tt * EPT + m;
      if (e >= N_EDGES) e = N_EDGES - 1;           // clamp (tail / prefetch OOB)
      const int iv = is64 ? eidx[6 * e + 2 + 2 * half]
                          : eidx[3 * e + 1 + half];
      const int fof = ((l15 * 16) ^ ((m & 7) << 4)) >> 1;  // pre-swizzled f32 off
      const float* src = zf + (size_t)iv * D_FEAT + fof;
      ga[ii] = *(const float4*)src;
      gb[ii] = *(const float4*)(src + 4);
    }
  };
  // convert + write a staged tile into LDS buffer `buf` (linear dest)
  auto lds_write = [&](int buf, const float4* ga, const float4* gb) {
    #pragma unroll
    for (int ii = 0; ii < 4; ++ii) {
      const int i = si + ii;
      *(uint4*)&sbuf[buf][i * 1024 + l * 16] = pack8(ga[ii], gb[ii]);
    }
  };

  // ---- prologue: stage tile t0; pre-gather tile t0+GRID ----
  const int t0 = blockIdx.x;
  float4 ga[4], gb[4];
  gather(t0, ga, gb);
  lds_write(0, ga, gb);
  gather(t0 + GRID_MAIN, ga, gb);
  __syncthreads();

  int it = 0;
  for (int t = t0; t < NTILES; t += GRID_MAIN, ++it) {
    const int cb  = it % 3;
    const int par = it & 1;

    // A: write tile t+GRID (gathered last iter) into next buffer
    lds_write((it + 1) % 3, ga, gb);
    // B: issue gathers for tile t+2*GRID (consumed next iter)
    gather(t + 2 * GRID_MAIN, ga, gb);

    // C: MFMA phase on sbuf[cb]
    f32x4 acc[2][4];
    #pragma unroll
    for (int rt = 0; rt < 2; ++rt)
      #pragma unroll
      for (int ct = 0; ct < 4; ++ct)
        acc[rt][ct] = (f32x4){0.f, 0.f, 0.f, 0.f};

    const unsigned char* sb = &sbuf[cb][0];
    #pragma unroll
    for (int ks = 0; ks < 8; ++ks) {
      bf16x8 bf[4];
      #pragma unroll
      for (int ct = 0; ct < 4; ++ct) {
        const int m    = ct * 16 + l15;
        const int phys = m * 512 + ((ks * 64 + g * 16) ^ ((m & 7) << 4));
        bf[ct] = *(const bf16x8*)(sb + phys);      // conflict-free ds_read_b128
      }
      __builtin_amdgcn_s_setprio(1);
      #pragma unroll
      for (int rt = 0; rt < 2; ++rt)
        #pragma unroll
        for (int ct = 0; ct < 4; ++ct)
          acc[rt][ct] = __builtin_amdgcn_mfma_f32_16x16x32_bf16(
              a[rt][ks], bf[ct], acc[rt][ct], 0, 0, 0);
      __builtin_amdgcn_s_setprio(0);
    }

    // D: bias + relu + fc2 partial dot; wave-partial into red[par]
    float p[4] = {0.f, 0.f, 0.f, 0.f};
    #pragma unroll
    for (int rt = 0; rt < 2; ++rt) {
      #pragma unroll
      for (int r = 0; r < 4; ++r) {
        const float bb = b1v[rt][r], w2r = w2v[rt][r];
        #pragma unroll
        for (int ct = 0; ct < 4; ++ct) {
          float x = acc[rt][ct][r] + bb;           // n = w*32+rt*16+g*4+r
          x = fmaxf(x, 0.f);
          p[ct] = fmaf(x, w2r, p[ct]);
        }
      }
    }
    #pragma unroll
    for (int ct = 0; ct < 4; ++ct) {               // sum the 4 k-slice groups
      p[ct] += __shfl_xor(p[ct], 16);
      p[ct] += __shfl_xor(p[ct], 32);
    }
    if (l < 16) {
      #pragma unroll
      for (int ct = 0; ct < 4; ++ct) red[par][w][ct * 16 + l] = p[ct];
    }

    // E: the single barrier
    __syncthreads();

    // F: distributed cross-wave sum + sigmoid; wave w handles edges [8w,8w+8)
    {
      const int el = 8 * w + (l & 7);
      float v = red[par][l >> 3][el];              // lane group l>>3 = wave idx
      v += __shfl_xor(v, 8);
      v += __shfl_xor(v, 16);
      v += __shfl_xor(v, 32);
      const int e = t * EPT + el;
      if (l < 8 && e < N_EDGES)
        out[e] = 1.f / (1.f + __expf(-(v + b2v)));
    }
  }
}

extern "C" void kernel_launch(void* const* d_in, const int* in_sizes, int n_in,
                              void* d_out, int out_size, void* d_ws, size_t ws_size,
                              hipStream_t stream) {
  const float* z    = (const float*)d_in[0];
  const int*   eidx = (const int*)d_in[1];
  const float* fc1w = (const float*)d_in[2];
  const float* fc1b = (const float*)d_in[3];
  const float* fc2w = (const float*)d_in[4];
  const float* fc2b = (const float*)d_in[5];
  float* out = (float*)d_out;

  mlp_fused<<<GRID_MAIN, 512, 0, stream>>>(eidx, z, fc1w, fc1b, fc2w, fc2b, out);
}